// Round 9
// baseline (250.957 us; speedup 1.0000x reference)
//
#include <hip/hip_runtime.h>
#include <hip/hip_bf16.h>
#include <math.h>
#include <stdint.h>

#define D_MODEL 768
#define D_STATE 16
#define D_INNER 1536
#define DT_RANK 48
#define BATCH   2
#define SEQ     1024
#define NROWS   (BATCH*SEQ)      // 2048
#define DBC_N   80
#define DBC_NP  128              // padded N for xproj MFMA
#define NCHUNK  64
#define CHUNK   16               // SEQ/NCHUNK
#define SCAN_G  (BATCH*NCHUNK*D_INNER)           // 196608 threads
#define SCAN_T  ((size_t)SCAN_G*D_STATE)         // 3145728 elems

typedef short short8 __attribute__((ext_vector_type(8)));
typedef float floatx4 __attribute__((ext_vector_type(4)));

__device__ __forceinline__ float siluf(float x){ return x / (1.0f + __expf(-x)); }
__device__ __forceinline__ short f2b(float f){
    union { __hip_bfloat16 h; short s; } u; u.h = __float2bfloat16(f); return u.s;
}
__device__ __forceinline__ float b2f(short s){
    union { short s; __hip_bfloat16 h; } u; u.s = s; return __bfloat162float(u.h);
}
__device__ __forceinline__ void gload_lds16(const void* g, void* l){
    auto gp = reinterpret_cast<const __attribute__((address_space(1))) uint32_t*>(
        reinterpret_cast<uintptr_t>(g));
    auto lp = reinterpret_cast<__attribute__((address_space(3))) uint32_t*>(
        reinterpret_cast<uintptr_t>(l));
    __builtin_amdgcn_global_load_lds(gp, lp, 16, 0, 0);
}

// ---------------- prep: rmsnorm + transposes + dbc zero + residual copy -------
__device__ __forceinline__ void transp32(const float* in, short* outT,
                                         int R, int C, int Cout,
                                         int bx, int by, int t,
                                         float (*tile)[33]){
    int c0 = bx*32, r0 = by*32;
    int tx = t & 31, ty = t >> 5;
    #pragma unroll
    for (int p = 0; p < 4; p++){
        int r = r0 + ty + p*8, c = c0 + tx;
        tile[ty+p*8][tx] = (r < R && c < C) ? in[(size_t)r*C + c] : 0.f;
    }
    __syncthreads();
    #pragma unroll
    for (int p = 0; p < 4; p++){
        int c = c0 + ty + p*8;
        int r = r0 + tx;
        if (c < Cout && r < R)
            outT[(size_t)c*R + r] = f2b(tile[tx][ty+p*8]);
    }
}

// grid = 2048 rms + 2304 w1 + 1152 w3 + 192 wx + 160 dbc-zero + 384 out-copy = 6240
__global__ __launch_bounds__(256) void k_prep(const float* __restrict__ x,
                                              const float* __restrict__ nw,
                                              short* __restrict__ hb,
                                              const float* __restrict__ w1, short* __restrict__ Wb1,
                                              const float* __restrict__ w3, short* __restrict__ Wb3,
                                              const float* __restrict__ wx, short* __restrict__ Wbx,
                                              float* __restrict__ dbc,
                                              float* __restrict__ out){
    __shared__ float tile[32][33];
    int bid = blockIdx.x, t = threadIdx.x;
    if (bid < 2048){
        const float* xr = x + (size_t)bid * D_MODEL;
        float v[3]; float ss = 0.f;
        #pragma unroll
        for (int i = 0; i < 3; i++){ v[i] = xr[t + i*256]; ss += v[i]*v[i]; }
        #pragma unroll
        for (int o = 1; o < 64; o <<= 1) ss += __shfl_xor(ss, o, 64);
        int wave = t >> 6, lane = t & 63;
        if (lane == 0) tile[0][wave] = ss;
        __syncthreads();
        float tot = tile[0][0] + tile[0][1] + tile[0][2] + tile[0][3];
        float scale = rsqrtf(tot * (1.0f/768.0f) + 1e-6f);
        #pragma unroll
        for (int i = 0; i < 3; i++){
            int idx = t + i*256;
            hb[(size_t)bid*D_MODEL + idx] = f2b(v[i] * scale * nw[idx]);
        }
    } else if (bid < 4352){
        int id = bid - 2048;
        transp32(w1, Wb1, 768, 3072, 3072, id % 96, id / 96, t, tile);
    } else if (bid < 5504){
        int id = bid - 4352;
        transp32(w3, Wb3, 1536, 768, 768, id % 24, id / 24, t, tile);
    } else if (bid < 5696){
        int id = bid - 5504;
        transp32(wx, Wbx, 1536, DBC_N, DBC_NP, id % 4, id / 4, t, tile);
    } else if (bid < 5856){
        int id = bid - 5696;                      // zero 2048*80 floats
        size_t base = (size_t)id*1024 + t*4;
        *(float4*)&dbc[base] = make_float4(0.f,0.f,0.f,0.f);
    } else {
        int id = bid - 5856;                      // out = x (residual preload)
        #pragma unroll
        for (int p = 0; p < 4; p++){
            size_t off = (size_t)id*4096 + p*1024 + t*4;
            *(float4*)&out[off] = *(const float4*)&x[off];
        }
    }
}

// ---------------- MFMA bf16 GEMM, A[M][K] bf16, Bt[N][K] bf16 -----------------
// MODE 1: fp32 + residual. 2: bf16 store. 3: fp32 atomicAdd (n<Nld).
template<int BM, int BN, int MODE, int KSPLIT>
__global__ __launch_bounds__(256) void k_mfma_bt(const short* __restrict__ A,
                                                 const short* __restrict__ Bt,
                                                 void* __restrict__ Cv,
                                                 const float* __restrict__ res,
                                                 int M, int N, int K, int Nld){
    constexpr int WM = BM/2, WN = BN/2;
    constexpr int FM = WM/16, FN = WN/16;
    constexpr int AU = BM*4;   // 16B staging units
    constexpr int BU = BN*4;
    __shared__ short As[BM*32];
    __shared__ short Bs[BN*32];
    int t = threadIdx.x;
    int wave = t >> 6, lane = t & 63;
    int lm = lane & 15, lq = lane >> 4;
    int row0 = blockIdx.y * BM, col0 = blockIdx.x * BN;
    int wr = (wave >> 1) * WM, wc = (wave & 1) * WN;
    int kper = K / KSPLIT;
    int kbeg = blockIdx.z * kper;
    floatx4 acc[FM][FN];
    #pragma unroll
    for (int mi = 0; mi < FM; mi++)
        #pragma unroll
        for (int ni = 0; ni < FN; ni++)
            acc[mi][ni] = (floatx4){0.f,0.f,0.f,0.f};

    for (int k0 = kbeg; k0 < kbeg + kper; k0 += 32){
        if constexpr (AU >= 256){
            #pragma unroll
            for (int r2 = 0; r2 < AU/256; r2++){
                int slot = r2*256 + t;
                int ar = slot >> 2, ak = (slot & 3)*8;
                gload_lds16(A + (size_t)(row0+ar)*K + k0 + ak, &As[slot*8]);
            }
        } else {
            if (t < AU){
                int ar = t >> 2, ak = (t & 3)*8;
                gload_lds16(A + (size_t)(row0+ar)*K + k0 + ak, &As[t*8]);
            }
        }
        if constexpr (BU >= 256){
            #pragma unroll
            for (int r2 = 0; r2 < BU/256; r2++){
                int slot = r2*256 + t;
                int br = slot >> 2, bk = (slot & 3)*8;
                gload_lds16(Bt + (size_t)(col0+br)*K + k0 + bk, &Bs[slot*8]);
            }
        } else {
            if (t < BU){
                int br = t >> 2, bk = (t & 3)*8;
                gload_lds16(Bt + (size_t)(col0+br)*K + k0 + bk, &Bs[t*8]);
            }
        }
        __syncthreads();
        short8 af[FM], bfr[FN];
        #pragma unroll
        for (int mi = 0; mi < FM; mi++)
            af[mi] = *(const short8*)&As[(wr + mi*16 + lm)*32 + lq*8];
        #pragma unroll
        for (int ni = 0; ni < FN; ni++)
            bfr[ni] = *(const short8*)&Bs[(wc + ni*16 + lm)*32 + lq*8];
        #pragma unroll
        for (int mi = 0; mi < FM; mi++)
            #pragma unroll
            for (int ni = 0; ni < FN; ni++)
                acc[mi][ni] = __builtin_amdgcn_mfma_f32_16x16x32_bf16(
                                  af[mi], bfr[ni], acc[mi][ni], 0, 0, 0);
        __syncthreads();
    }
    float* Cf = (float*)Cv;
    short* Cs = (short*)Cv;
    #pragma unroll
    for (int mi = 0; mi < FM; mi++)
        #pragma unroll
        for (int ni = 0; ni < FN; ni++)
            #pragma unroll
            for (int r = 0; r < 4; r++){
                int m = row0 + wr + mi*16 + lq*4 + r;
                int n = col0 + wc + ni*16 + lm;
                float v = acc[mi][ni][r];
                if constexpr (MODE == 1){
                    Cf[(size_t)m*Nld + n] = v + res[(size_t)m*Nld + n];
                } else if constexpr (MODE == 2){
                    Cs[(size_t)m*Nld + n] = f2b(v);
                } else {
                    if (n < Nld) atomicAdd(&Cf[(size_t)m*Nld + n], v);
                }
            }
}

// ---------------- xproj GEMM with conv+SiLU fused into A-staging --------------
// A = xc = silu(depthwise_conv(xz x-half) + cb), computed during staging and
// also written to xcb (duplicate identical writes from the 2 N-tiles: benign).
// grid (DBC_NP/64, NROWS/64, 8); dbc must be pre-zeroed (atomic epilogue).
__global__ __launch_bounds__(256) void k_xproj_conv(const short* __restrict__ xzb,
                                                    const float* __restrict__ cw,
                                                    const float* __restrict__ cb,
                                                    const short* __restrict__ Bt,
                                                    float* __restrict__ dbc,
                                                    short* __restrict__ xcb){
    __shared__ short As[64*32];
    __shared__ short Bs[64*32];
    int t = threadIdx.x;
    int wave = t >> 6, lane = t & 63;
    int lm = lane & 15, lq = lane >> 4;
    int row0 = blockIdx.y * 64, col0 = blockIdx.x * 64;
    int wr = (wave >> 1) * 32, wc = (wave & 1) * 32;
    int kbeg = blockIdx.z * (D_INNER/8);          // 192-wide K slice
    floatx4 acc[2][2];
    #pragma unroll
    for (int mi = 0; mi < 2; mi++)
        #pragma unroll
        for (int ni = 0; ni < 2; ni++)
            acc[mi][ni] = (floatx4){0.f,0.f,0.f,0.f};

    for (int k0 = kbeg; k0 < kbeg + D_INNER/8; k0 += 32){
        // B staging (async)
        {
            int br = t >> 2, bk = (t & 3)*8;
            gload_lds16(Bt + (size_t)(col0+br)*D_INNER + k0 + bk, &Bs[t*8]);
        }
        // A staging via conv: 64 rows x 32 channels, 8 elems/thread
        #pragma unroll
        for (int e8 = 0; e8 < 8; e8++){
            int e = e8*256 + t;
            int row = e >> 5, dcol = e & 31;
            int d = k0 + dcol;
            int r = row0 + row;
            int l = r & (SEQ-1);
            float acc2 = cb[d];
            #pragma unroll
            for (int k = 0; k < 4; k++){
                int lt = l - 3 + k;
                if (lt >= 0)
                    acc2 += b2f(xzb[(size_t)(r-3+k)*3072 + d]) * cw[d*4 + k];
            }
            short sv = f2b(siluf(acc2));
            As[e] = sv;
            xcb[(size_t)r*D_INNER + d] = sv;
        }
        __syncthreads();
        short8 af[2], bfr[2];
        #pragma unroll
        for (int mi = 0; mi < 2; mi++)
            af[mi] = *(const short8*)&As[(wr + mi*16 + lm)*32 + lq*8];
        #pragma unroll
        for (int ni = 0; ni < 2; ni++)
            bfr[ni] = *(const short8*)&Bs[(wc + ni*16 + lm)*32 + lq*8];
        #pragma unroll
        for (int mi = 0; mi < 2; mi++)
            #pragma unroll
            for (int ni = 0; ni < 2; ni++)
                acc[mi][ni] = __builtin_amdgcn_mfma_f32_16x16x32_bf16(
                                  af[mi], bfr[ni], acc[mi][ni], 0, 0, 0);
        __syncthreads();
    }
    #pragma unroll
    for (int mi = 0; mi < 2; mi++)
        #pragma unroll
        for (int ni = 0; ni < 2; ni++)
            #pragma unroll
            for (int r = 0; r < 4; r++){
                int m = row0 + wr + mi*16 + lq*4 + r;
                int n = col0 + wc + ni*16 + lm;
                if (n < DBC_N)
                    atomicAdd(&dbc[(size_t)m*DBC_N + n], acc[mi][ni][r]);
            }
}

// ================= chunked selective scan (dtproj fused into phase A) =========
// thread t = (b*NCHUNK + chunk)*D_INNER + d; Ap/Hl/carry bf16, layout [t][n].

__global__ __launch_bounds__(256) void k_scanA(const short* __restrict__ xcb,
                                               const float* __restrict__ dbc,
                                               const float* __restrict__ wdt,
                                               const float* __restrict__ bdt,
                                               const float* __restrict__ A_log,
                                               short* __restrict__ Apb,
                                               short* __restrict__ Hlb,
                                               short* __restrict__ dtb){
    int t = blockIdx.x * 256 + threadIdx.x;
    int d = t % D_INNER;
    int bc = t / D_INNER;
    int chunk = bc % NCHUNK, b = bc / NCHUNK;
    int r0 = b*SEQ + chunk*CHUNK;

    float dt16[CHUNK];
    {
        float wr[DT_RANK];
        #pragma unroll
        for (int k = 0; k < DT_RANK; k++) wr[k] = wdt[k*D_INNER + d];
        float bj = bdt[d];
        for (int l = 0; l < CHUNK; l++){
            const float* dl = &dbc[(size_t)(r0+l)*DBC_N];   // wave-uniform bcast
            float acc = bj;
            #pragma unroll
            for (int k = 0; k < DT_RANK; k++) acc += dl[k] * wr[k];
            float sp = (acc > 20.f) ? acc : __logf(1.f + __expf(acc));
            dt16[l] = sp;
            dtb[(size_t)(r0+l)*D_INNER + d] = f2b(sp);
        }
    }

    float A[16], h[16], aP[16];
    const float4* al = (const float4*)&A_log[d*D_STATE];
    #pragma unroll
    for (int i = 0; i < 4; i++){
        float4 v = al[i];
        A[4*i+0] = -__expf(v.x); A[4*i+1] = -__expf(v.y);
        A[4*i+2] = -__expf(v.z); A[4*i+3] = -__expf(v.w);
    }
    #pragma unroll
    for (int n = 0; n < 16; n++){ h[n] = 0.f; aP[n] = 1.f; }
    for (int l = 0; l < CHUNK; l++){
        int r = r0 + l;
        float dtv = dt16[l];
        float xcv = b2f(xcb[(size_t)r*D_INNER + d]);
        const float4* bp = (const float4*)&dbc[(size_t)r*DBC_N + DT_RANK];
        float Bm[16];
        #pragma unroll
        for (int i = 0; i < 4; i++){
            float4 v = bp[i];
            Bm[4*i+0]=v.x; Bm[4*i+1]=v.y; Bm[4*i+2]=v.z; Bm[4*i+3]=v.w;
        }
        float comm = dtv * xcv;
        #pragma unroll
        for (int n = 0; n < 16; n++){
            float a = __expf(dtv * A[n]);
            h[n] = a*h[n] + comm*Bm[n];
            aP[n] *= a;
        }
    }
    short8 s0, s1;
    #pragma unroll
    for (int i = 0; i < 8; i++){ s0[i] = f2b(aP[i]);  s1[i] = f2b(aP[8+i]); }
    *(short8*)&Apb[(size_t)t*16]     = s0;
    *(short8*)&Apb[(size_t)t*16 + 8] = s1;
    #pragma unroll
    for (int i = 0; i < 8; i++){ s0[i] = f2b(h[i]);   s1[i] = f2b(h[8+i]); }
    *(short8*)&Hlb[(size_t)t*16]     = s0;
    *(short8*)&Hlb[(size_t)t*16 + 8] = s1;
}

// carry aliases Apb: each idx read before written.
__global__ __launch_bounds__(256) void k_scanB(const short* Apb,
                                               const short* Hlb,
                                               short* carry){
    int t = blockIdx.x * 256 + threadIdx.x;    // over [b][d][n] = 49152
    int dn = t % (D_INNER*16);
    int b  = t / (D_INNER*16);
    float c = 0.f;
    #pragma unroll 4
    for (int ch = 0; ch < NCHUNK; ch++){
        size_t idx = ((size_t)((b*NCHUNK + ch)*D_INNER))*16 + dn;
        float a  = b2f(Apb[idx]);
        float hl = b2f(Hlb[idx]);
        carry[idx] = f2b(c);
        c = a*c + hl;
    }
}

__global__ __launch_bounds__(256) void k_scanC(const short* __restrict__ dtb,
                                               const short* __restrict__ xcb,
                                               const float* __restrict__ dbc,
                                               const short* __restrict__ xzb,
                                               const float* __restrict__ A_log,
                                               const float* __restrict__ Dp,
                                               const short* __restrict__ carry,
                                               short* __restrict__ yb){
    int t = blockIdx.x * 256 + threadIdx.x;
    int d = t % D_INNER;
    int bc = t / D_INNER;
    int chunk = bc % NCHUNK, b = bc / NCHUNK;
    float A[16], h[16];
    const float4* al = (const float4*)&A_log[d*D_STATE];
    #pragma unroll
    for (int i = 0; i < 4; i++){
        float4 v = al[i];
        A[4*i+0] = -__expf(v.x); A[4*i+1] = -__expf(v.y);
        A[4*i+2] = -__expf(v.z); A[4*i+3] = -__expf(v.w);
    }
    {
        short8 c0 = *(const short8*)&carry[(size_t)t*16];
        short8 c1 = *(const short8*)&carry[(size_t)t*16 + 8];
        #pragma unroll
        for (int i = 0; i < 8; i++){ h[i] = b2f(c0[i]); h[8+i] = b2f(c1[i]); }
    }
    float Dv = Dp[d];
    int r0 = b*SEQ + chunk*CHUNK;
    for (int l = 0; l < CHUNK; l++){
        int r = r0 + l;
        float dtv = b2f(dtb[(size_t)r*D_INNER + d]);
        float xcv = b2f(xcb[(size_t)r*D_INNER + d]);
        const float4* bp = (const float4*)&dbc[(size_t)r*DBC_N + DT_RANK];
        float Bm[16], Cm[16];
        #pragma unroll
        for (int i = 0; i < 4; i++){
            float4 v = bp[i];
            Bm[4*i+0]=v.x; Bm[4*i+1]=v.y; Bm[4*i+2]=v.z; Bm[4*i+3]=v.w;
            float4 w = bp[4+i];
            Cm[4*i+0]=w.x; Cm[4*i+1]=w.y; Cm[4*i+2]=w.z; Cm[4*i+3]=w.w;
        }
        float comm = dtv * xcv;
        float yv = 0.f;
        #pragma unroll
        for (int n = 0; n < 16; n++){
            float a = __expf(dtv * A[n]);
            h[n] = a*h[n] + comm*Bm[n];
            yv += h[n]*Cm[n];
        }
        float z = b2f(xzb[(size_t)r*(2*D_INNER) + D_INNER + d]);
        yb[(size_t)r*D_INNER + d] = f2b((yv + Dv*xcv) * siluf(z));
    }
}

extern "C" void kernel_launch(void* const* d_in, const int* in_sizes, int n_in,
                              void* d_out, int out_size, void* d_ws, size_t ws_size,
                              hipStream_t stream) {
    const float* x         = (const float*)d_in[0];
    const float* norm_w    = (const float*)d_in[1];
    const float* in_proj_w = (const float*)d_in[2];
    const float* conv_w    = (const float*)d_in[3];
    const float* conv_b    = (const float*)d_in[4];
    const float* x_proj_w  = (const float*)d_in[5];
    const float* dt_proj_w = (const float*)d_in[6];
    const float* dt_proj_b = (const float*)d_in[7];
    const float* A_log     = (const float*)d_in[8];
    const float* Dp        = (const float*)d_in[9];
    const float* out_proj_w= (const float*)d_in[10];
    float* out = (float*)d_out;

    char* p = (char*)d_ws;
    short* hb  = (short*)p; p += (size_t)NROWS*D_MODEL*2;
    short* xzb = (short*)p; p += (size_t)NROWS*3072*2;
    short* xcb = (short*)p; p += (size_t)NROWS*D_INNER*2;
    float* dbc = (float*)p; p += (size_t)NROWS*DBC_N*4;
    short* dtb = (short*)p; p += (size_t)NROWS*D_INNER*2;
    short* yb  = (short*)p; p += (size_t)NROWS*D_INNER*2;
    short* Apb = (short*)p; p += SCAN_T*2;                     // aliased as carry
    short* Hlb = (short*)p; p += SCAN_T*2;
    short* Wb1 = (short*)p; p += (size_t)3072*768*2;
    short* Wb3 = (short*)p; p += (size_t)768*1536*2;
    short* Wbx = (short*)p; p += (size_t)DBC_NP*1536*2;
    short* cr  = Apb;  // alias: k_scanB reads before writing at each idx

    // rmsnorm + transposes + dbc zero + residual preload into out
    k_prep<<<6240, 256, 0, stream>>>(x, norm_w, hb, in_proj_w, Wb1,
                                     out_proj_w, Wb3, x_proj_w, Wbx, dbc, out);

    // in-proj: M=2048, N=3072, K=768, 128x64 tiles -> 768 blocks, bf16 out
    k_mfma_bt<128,64,2,1><<<dim3(3072/64, NROWS/128), 256, 0, stream>>>(
        hb, Wb1, xzb, nullptr, NROWS, 3072, D_MODEL, 3072);

    // x-proj with fused conv+SiLU: split-K=8 -> 512 blocks; writes xcb + dbc
    k_xproj_conv<<<dim3(DBC_NP/64, NROWS/64, 8), 256, 0, stream>>>(
        xzb, conv_w, conv_b, Wbx, dbc, xcb);

    // scan: A (dtproj fused) -> B -> C   (bf16 intermediates)
    k_scanA<<<SCAN_G/256, 256, 0, stream>>>(xcb, dbc, dt_proj_w, dt_proj_b,
                                            A_log, Apb, Hlb, dtb);
    k_scanB<<<(BATCH*D_INNER*D_STATE)/256, 256, 0, stream>>>(Apb, Hlb, cr);
    k_scanC<<<SCAN_G/256, 256, 0, stream>>>(dtb, xcb, dbc, xzb, A_log, Dp,
                                            cr, yb);

    // out-proj: M=2048, N=768, K=1536, split-K=2 -> 768 blocks, atomicAdd
    // (residual preloaded into out by k_prep)
    k_mfma_bt<64,64,3,2><<<dim3(768/64, NROWS/64, 2), 256, 0, stream>>>(
        yb, Wb3, out, nullptr, NROWS, 768, D_INNER, 768);
}

// Round 10
// 232.580 us; speedup vs baseline: 1.0790x; 1.0790x over previous
//
#include <hip/hip_runtime.h>
#include <hip/hip_bf16.h>
#include <math.h>
#include <stdint.h>

#define D_MODEL 768
#define D_STATE 16
#define D_INNER 1536
#define DT_RANK 48
#define BATCH   2
#define SEQ     1024
#define NROWS   (BATCH*SEQ)      // 2048
#define DBC_N   80
#define DBC_NP  128              // padded N for xproj MFMA
#define NCHUNK  64
#define CHUNK   16               // SEQ/NCHUNK
#define SCAN_G  (BATCH*NCHUNK*D_INNER)           // 196608 threads
#define SCAN_T  ((size_t)SCAN_G*D_STATE)         // 3145728 elems

typedef short short8 __attribute__((ext_vector_type(8)));
typedef float floatx4 __attribute__((ext_vector_type(4)));

__device__ __forceinline__ float siluf(float x){ return x / (1.0f + __expf(-x)); }
__device__ __forceinline__ short f2b(float f){
    union { __hip_bfloat16 h; short s; } u; u.h = __float2bfloat16(f); return u.s;
}
__device__ __forceinline__ float b2f(short s){
    union { short s; __hip_bfloat16 h; } u; u.s = s; return __bfloat162float(u.h);
}
__device__ __forceinline__ void gload_lds16(const void* g, void* l){
    auto gp = reinterpret_cast<const __attribute__((address_space(1))) uint32_t*>(
        reinterpret_cast<uintptr_t>(g));
    auto lp = reinterpret_cast<__attribute__((address_space(3))) uint32_t*>(
        reinterpret_cast<uintptr_t>(l));
    __builtin_amdgcn_global_load_lds(gp, lp, 16, 0, 0);
}

// ---------------- prep: rmsnorm + transposes + dbc zero + residual copy -------
__device__ __forceinline__ void transp32(const float* in, short* outT,
                                         int R, int C, int Cout,
                                         int bx, int by, int t,
                                         float (*tile)[33]){
    int c0 = bx*32, r0 = by*32;
    int tx = t & 31, ty = t >> 5;
    #pragma unroll
    for (int p = 0; p < 4; p++){
        int r = r0 + ty + p*8, c = c0 + tx;
        tile[ty+p*8][tx] = (r < R && c < C) ? in[(size_t)r*C + c] : 0.f;
    }
    __syncthreads();
    #pragma unroll
    for (int p = 0; p < 4; p++){
        int c = c0 + ty + p*8;
        int r = r0 + tx;
        if (c < Cout && r < R)
            outT[(size_t)c*R + r] = f2b(tile[tx][ty+p*8]);
    }
}

// grid = 2048 rms + 2304 w1 + 1152 w3 + 192 wx + 160 dbc-zero + 384 out-copy = 6240
__global__ __launch_bounds__(256) void k_prep(const float* __restrict__ x,
                                              const float* __restrict__ nw,
                                              short* __restrict__ hb,
                                              const float* __restrict__ w1, short* __restrict__ Wb1,
                                              const float* __restrict__ w3, short* __restrict__ Wb3,
                                              const float* __restrict__ wx, short* __restrict__ Wbx,
                                              float* __restrict__ dbc,
                                              float* __restrict__ out){
    __shared__ float tile[32][33];
    int bid = blockIdx.x, t = threadIdx.x;
    if (bid < 2048){
        const float* xr = x + (size_t)bid * D_MODEL;
        float v[3]; float ss = 0.f;
        #pragma unroll
        for (int i = 0; i < 3; i++){ v[i] = xr[t + i*256]; ss += v[i]*v[i]; }
        #pragma unroll
        for (int o = 1; o < 64; o <<= 1) ss += __shfl_xor(ss, o, 64);
        int wave = t >> 6, lane = t & 63;
        if (lane == 0) tile[0][wave] = ss;
        __syncthreads();
        float tot = tile[0][0] + tile[0][1] + tile[0][2] + tile[0][3];
        float scale = rsqrtf(tot * (1.0f/768.0f) + 1e-6f);
        #pragma unroll
        for (int i = 0; i < 3; i++){
            int idx = t + i*256;
            hb[(size_t)bid*D_MODEL + idx] = f2b(v[i] * scale * nw[idx]);
        }
    } else if (bid < 4352){
        int id = bid - 2048;
        transp32(w1, Wb1, 768, 3072, 3072, id % 96, id / 96, t, tile);
    } else if (bid < 5504){
        int id = bid - 4352;
        transp32(w3, Wb3, 1536, 768, 768, id % 24, id / 24, t, tile);
    } else if (bid < 5696){
        int id = bid - 5504;
        transp32(wx, Wbx, 1536, DBC_N, DBC_NP, id % 4, id / 4, t, tile);
    } else if (bid < 5856){
        int id = bid - 5696;                      // zero 2048*80 floats
        size_t base = (size_t)id*1024 + t*4;
        *(float4*)&dbc[base] = make_float4(0.f,0.f,0.f,0.f);
    } else {
        int id = bid - 5856;                      // out = x (residual preload)
        #pragma unroll
        for (int p = 0; p < 4; p++){
            size_t off = (size_t)id*4096 + p*1024 + t*4;
            *(float4*)&out[off] = *(const float4*)&x[off];
        }
    }
}

// ---------------- MFMA bf16 GEMM, A[M][K] bf16, Bt[N][K] bf16 -----------------
// MODE 2: bf16 store. 3: fp32 atomicAdd (n<Nld).
template<int BM, int BN, int MODE, int KSPLIT>
__global__ __launch_bounds__(256) void k_mfma_bt(const short* __restrict__ A,
                                                 const short* __restrict__ Bt,
                                                 void* __restrict__ Cv,
                                                 int M, int N, int K, int Nld){
    constexpr int WM = BM/2, WN = BN/2;
    constexpr int FM = WM/16, FN = WN/16;
    constexpr int AU = BM*4;   // 16B staging units
    constexpr int BU = BN*4;
    __shared__ short As[BM*32];
    __shared__ short Bs[BN*32];
    int t = threadIdx.x;
    int wave = t >> 6, lane = t & 63;
    int lm = lane & 15, lq = lane >> 4;
    int row0 = blockIdx.y * BM, col0 = blockIdx.x * BN;
    int wr = (wave >> 1) * WM, wc = (wave & 1) * WN;
    int kper = K / KSPLIT;
    int kbeg = blockIdx.z * kper;
    floatx4 acc[FM][FN];
    #pragma unroll
    for (int mi = 0; mi < FM; mi++)
        #pragma unroll
        for (int ni = 0; ni < FN; ni++)
            acc[mi][ni] = (floatx4){0.f,0.f,0.f,0.f};

    for (int k0 = kbeg; k0 < kbeg + kper; k0 += 32){
        if constexpr (AU >= 256){
            #pragma unroll
            for (int r2 = 0; r2 < AU/256; r2++){
                int slot = r2*256 + t;
                int ar = slot >> 2, ak = (slot & 3)*8;
                gload_lds16(A + (size_t)(row0+ar)*K + k0 + ak, &As[slot*8]);
            }
        } else {
            if (t < AU){
                int ar = t >> 2, ak = (t & 3)*8;
                gload_lds16(A + (size_t)(row0+ar)*K + k0 + ak, &As[t*8]);
            }
        }
        if constexpr (BU >= 256){
            #pragma unroll
            for (int r2 = 0; r2 < BU/256; r2++){
                int slot = r2*256 + t;
                int br = slot >> 2, bk = (slot & 3)*8;
                gload_lds16(Bt + (size_t)(col0+br)*K + k0 + bk, &Bs[slot*8]);
            }
        } else {
            if (t < BU){
                int br = t >> 2, bk = (t & 3)*8;
                gload_lds16(Bt + (size_t)(col0+br)*K + k0 + bk, &Bs[t*8]);
            }
        }
        __syncthreads();
        short8 af[FM], bfr[FN];
        #pragma unroll
        for (int mi = 0; mi < FM; mi++)
            af[mi] = *(const short8*)&As[(wr + mi*16 + lm)*32 + lq*8];
        #pragma unroll
        for (int ni = 0; ni < FN; ni++)
            bfr[ni] = *(const short8*)&Bs[(wc + ni*16 + lm)*32 + lq*8];
        #pragma unroll
        for (int mi = 0; mi < FM; mi++)
            #pragma unroll
            for (int ni = 0; ni < FN; ni++)
                acc[mi][ni] = __builtin_amdgcn_mfma_f32_16x16x32_bf16(
                                  af[mi], bfr[ni], acc[mi][ni], 0, 0, 0);
        __syncthreads();
    }
    float* Cf = (float*)Cv;
    short* Cs = (short*)Cv;
    #pragma unroll
    for (int mi = 0; mi < FM; mi++)
        #pragma unroll
        for (int ni = 0; ni < FN; ni++)
            #pragma unroll
            for (int r = 0; r < 4; r++){
                int m = row0 + wr + mi*16 + lq*4 + r;
                int n = col0 + wc + ni*16 + lm;
                float v = acc[mi][ni][r];
                if constexpr (MODE == 2){
                    Cs[(size_t)m*Nld + n] = f2b(v);
                } else {
                    if (n < Nld) atomicAdd(&Cf[(size_t)m*Nld + n], v);
                }
            }
}

// ---------------- causal depthwise conv + bias + SiLU -> bf16 -----------------
__global__ __launch_bounds__(256) void k_conv(const short* __restrict__ xzb,
                                              const float* __restrict__ cw,
                                              const float* __restrict__ cb,
                                              short* __restrict__ xcb){
    int idx = blockIdx.x * 256 + threadIdx.x;   // over NROWS*D_INNER
    int d = idx % D_INNER;
    int r = idx / D_INNER;
    int l = r % SEQ;
    float acc = cb[d];
    #pragma unroll
    for (int k = 0; k < 4; k++){
        int ls = l - 3 + k;
        if (ls >= 0)
            acc += b2f(xzb[(size_t)(r - 3 + k)*3072 + d]) * cw[d*4 + k];
    }
    xcb[idx] = f2b(siluf(acc));
}

// ================= chunked selective scan (dtproj fused into phase A) =========
// thread t = (b*NCHUNK + chunk)*D_INNER + d; Ap/Hl/carry bf16, layout [t][n].

__global__ __launch_bounds__(256) void k_scanA(const short* __restrict__ xcb,
                                               const float* __restrict__ dbc,
                                               const float* __restrict__ wdt,
                                               const float* __restrict__ bdt,
                                               const float* __restrict__ A_log,
                                               short* __restrict__ Apb,
                                               short* __restrict__ Hlb,
                                               short* __restrict__ dtb){
    int t = blockIdx.x * 256 + threadIdx.x;
    int d = t % D_INNER;
    int bc = t / D_INNER;
    int chunk = bc % NCHUNK, b = bc / NCHUNK;
    int r0 = b*SEQ + chunk*CHUNK;

    float dt16[CHUNK];
    {
        float wr[DT_RANK];
        #pragma unroll
        for (int k = 0; k < DT_RANK; k++) wr[k] = wdt[k*D_INNER + d];
        float bj = bdt[d];
        for (int l = 0; l < CHUNK; l++){
            const float* dl = &dbc[(size_t)(r0+l)*DBC_N];   // wave-uniform bcast
            float acc = bj;
            #pragma unroll
            for (int k = 0; k < DT_RANK; k++) acc += dl[k] * wr[k];
            float sp = (acc > 20.f) ? acc : __logf(1.f + __expf(acc));
            dt16[l] = sp;
            dtb[(size_t)(r0+l)*D_INNER + d] = f2b(sp);
        }
    }

    float A[16], h[16], aP[16];
    const float4* al = (const float4*)&A_log[d*D_STATE];
    #pragma unroll
    for (int i = 0; i < 4; i++){
        float4 v = al[i];
        A[4*i+0] = -__expf(v.x); A[4*i+1] = -__expf(v.y);
        A[4*i+2] = -__expf(v.z); A[4*i+3] = -__expf(v.w);
    }
    #pragma unroll
    for (int n = 0; n < 16; n++){ h[n] = 0.f; aP[n] = 1.f; }
    for (int l = 0; l < CHUNK; l++){
        int r = r0 + l;
        float dtv = dt16[l];
        float xcv = b2f(xcb[(size_t)r*D_INNER + d]);
        const float4* bp = (const float4*)&dbc[(size_t)r*DBC_N + DT_RANK];
        float Bm[16];
        #pragma unroll
        for (int i = 0; i < 4; i++){
            float4 v = bp[i];
            Bm[4*i+0]=v.x; Bm[4*i+1]=v.y; Bm[4*i+2]=v.z; Bm[4*i+3]=v.w;
        }
        float comm = dtv * xcv;
        #pragma unroll
        for (int n = 0; n < 16; n++){
            float a = __expf(dtv * A[n]);
            h[n] = a*h[n] + comm*Bm[n];
            aP[n] *= a;
        }
    }
    short8 s0, s1;
    #pragma unroll
    for (int i = 0; i < 8; i++){ s0[i] = f2b(aP[i]);  s1[i] = f2b(aP[8+i]); }
    *(short8*)&Apb[(size_t)t*16]     = s0;
    *(short8*)&Apb[(size_t)t*16 + 8] = s1;
    #pragma unroll
    for (int i = 0; i < 8; i++){ s0[i] = f2b(h[i]);   s1[i] = f2b(h[8+i]); }
    *(short8*)&Hlb[(size_t)t*16]     = s0;
    *(short8*)&Hlb[(size_t)t*16 + 8] = s1;
}

// carry aliases Apb: each idx read before written.
__global__ __launch_bounds__(256) void k_scanB(const short* Apb,
                                               const short* Hlb,
                                               short* carry){
    int t = blockIdx.x * 256 + threadIdx.x;    // over [b][d][n] = 49152
    int dn = t % (D_INNER*16);
    int b  = t / (D_INNER*16);
    float c = 0.f;
    #pragma unroll 4
    for (int ch = 0; ch < NCHUNK; ch++){
        size_t idx = ((size_t)((b*NCHUNK + ch)*D_INNER))*16 + dn;
        float a  = b2f(Apb[idx]);
        float hl = b2f(Hlb[idx]);
        carry[idx] = f2b(c);
        c = a*c + hl;
    }
}

__global__ __launch_bounds__(256) void k_scanC(const short* __restrict__ dtb,
                                               const short* __restrict__ xcb,
                                               const float* __restrict__ dbc,
                                               const short* __restrict__ xzb,
                                               const float* __restrict__ A_log,
                                               const float* __restrict__ Dp,
                                               const short* __restrict__ carry,
                                               short* __restrict__ yb){
    int t = blockIdx.x * 256 + threadIdx.x;
    int d = t % D_INNER;
    int bc = t / D_INNER;
    int chunk = bc % NCHUNK, b = bc / NCHUNK;
    float A[16], h[16];
    const float4* al = (const float4*)&A_log[d*D_STATE];
    #pragma unroll
    for (int i = 0; i < 4; i++){
        float4 v = al[i];
        A[4*i+0] = -__expf(v.x); A[4*i+1] = -__expf(v.y);
        A[4*i+2] = -__expf(v.z); A[4*i+3] = -__expf(v.w);
    }
    {
        short8 c0 = *(const short8*)&carry[(size_t)t*16];
        short8 c1 = *(const short8*)&carry[(size_t)t*16 + 8];
        #pragma unroll
        for (int i = 0; i < 8; i++){ h[i] = b2f(c0[i]); h[8+i] = b2f(c1[i]); }
    }
    float Dv = Dp[d];
    int r0 = b*SEQ + chunk*CHUNK;
    for (int l = 0; l < CHUNK; l++){
        int r = r0 + l;
        float dtv = b2f(dtb[(size_t)r*D_INNER + d]);
        float xcv = b2f(xcb[(size_t)r*D_INNER + d]);
        const float4* bp = (const float4*)&dbc[(size_t)r*DBC_N + DT_RANK];
        float Bm[16], Cm[16];
        #pragma unroll
        for (int i = 0; i < 4; i++){
            float4 v = bp[i];
            Bm[4*i+0]=v.x; Bm[4*i+1]=v.y; Bm[4*i+2]=v.z; Bm[4*i+3]=v.w;
            float4 w = bp[4+i];
            Cm[4*i+0]=w.x; Cm[4*i+1]=w.y; Cm[4*i+2]=w.z; Cm[4*i+3]=w.w;
        }
        float comm = dtv * xcv;
        float yv = 0.f;
        #pragma unroll
        for (int n = 0; n < 16; n++){
            float a = __expf(dtv * A[n]);
            h[n] = a*h[n] + comm*Bm[n];
            yv += h[n]*Cm[n];
        }
        float z = b2f(xzb[(size_t)r*(2*D_INNER) + D_INNER + d]);
        yb[(size_t)r*D_INNER + d] = f2b((yv + Dv*xcv) * siluf(z));
    }
}

extern "C" void kernel_launch(void* const* d_in, const int* in_sizes, int n_in,
                              void* d_out, int out_size, void* d_ws, size_t ws_size,
                              hipStream_t stream) {
    const float* x         = (const float*)d_in[0];
    const float* norm_w    = (const float*)d_in[1];
    const float* in_proj_w = (const float*)d_in[2];
    const float* conv_w    = (const float*)d_in[3];
    const float* conv_b    = (const float*)d_in[4];
    const float* x_proj_w  = (const float*)d_in[5];
    const float* dt_proj_w = (const float*)d_in[6];
    const float* dt_proj_b = (const float*)d_in[7];
    const float* A_log     = (const float*)d_in[8];
    const float* Dp        = (const float*)d_in[9];
    const float* out_proj_w= (const float*)d_in[10];
    float* out = (float*)d_out;

    char* p = (char*)d_ws;
    short* hb  = (short*)p; p += (size_t)NROWS*D_MODEL*2;
    short* xzb = (short*)p; p += (size_t)NROWS*3072*2;
    short* xcb = (short*)p; p += (size_t)NROWS*D_INNER*2;
    float* dbc = (float*)p; p += (size_t)NROWS*DBC_N*4;
    short* dtb = (short*)p; p += (size_t)NROWS*D_INNER*2;
    short* yb  = (short*)p; p += (size_t)NROWS*D_INNER*2;
    short* Apb = (short*)p; p += SCAN_T*2;                     // aliased as carry
    short* Hlb = (short*)p; p += SCAN_T*2;
    short* Wb1 = (short*)p; p += (size_t)3072*768*2;
    short* Wb3 = (short*)p; p += (size_t)768*1536*2;
    short* Wbx = (short*)p; p += (size_t)DBC_NP*1536*2;
    short* cr  = Apb;  // alias: k_scanB reads before writing at each idx

    // rmsnorm + transposes + dbc zero + residual preload into out
    k_prep<<<6240, 256, 0, stream>>>(x, norm_w, hb, in_proj_w, Wb1,
                                     out_proj_w, Wb3, x_proj_w, Wbx, dbc, out);

    // in-proj: M=2048, N=3072, K=768, 128x64 tiles -> 768 blocks, bf16 out
    k_mfma_bt<128,64,2,1><<<dim3(3072/64, NROWS/128), 256, 0, stream>>>(
        hb, Wb1, xzb, NROWS, 3072, D_MODEL, 3072);

    // conv (coalesced, streaming)
    k_conv<<<(NROWS*D_INNER)/256, 256, 0, stream>>>(xzb, conv_w, conv_b, xcb);

    // x-proj: M=2048, N=128(pad of 80), K=1536, split-K=8 -> 512 blocks
    k_mfma_bt<64,64,3,8><<<dim3(DBC_NP/64, NROWS/64, 8), 256, 0, stream>>>(
        xcb, Wbx, dbc, NROWS, DBC_NP, D_INNER, DBC_N);

    // scan: A (dtproj fused) -> B -> C   (bf16 intermediates)
    k_scanA<<<SCAN_G/256, 256, 0, stream>>>(xcb, dbc, dt_proj_w, dt_proj_b,
                                            A_log, Apb, Hlb, dtb);
    k_scanB<<<(BATCH*D_INNER*D_STATE)/256, 256, 0, stream>>>(Apb, Hlb, cr);
    k_scanC<<<SCAN_G/256, 256, 0, stream>>>(dtb, xcb, dbc, xzb, A_log, Dp,
                                            cr, yb);

    // out-proj: M=2048, N=768, K=1536, split-K=2 -> 768 blocks, atomicAdd
    // (residual preloaded into out by k_prep)
    k_mfma_bt<64,64,3,2><<<dim3(768/64, NROWS/64, 2), 256, 0, stream>>>(
        yb, Wb3, out, NROWS, 768, D_INNER, 768);
}

// Round 11
// 226.158 us; speedup vs baseline: 1.1097x; 1.0284x over previous
//
#include <hip/hip_runtime.h>
#include <hip/hip_bf16.h>
#include <math.h>
#include <stdint.h>

#define D_MODEL 768
#define D_STATE 16
#define D_INNER 1536
#define DT_RANK 48
#define BATCH   2
#define SEQ     1024
#define NROWS   (BATCH*SEQ)      // 2048
#define DBC_N   80
#define DBC_NP  128              // padded N for xproj MFMA
#define NCHUNK  64
#define CHUNK   16               // SEQ/NCHUNK
#define SCAN_G  (BATCH*NCHUNK*D_INNER)           // 196608 threads
#define SCAN_T  ((size_t)SCAN_G*D_STATE)         // 3145728 elems

typedef short short8 __attribute__((ext_vector_type(8)));
typedef float floatx4 __attribute__((ext_vector_type(4)));

__device__ __forceinline__ float siluf(float x){ return x / (1.0f + __expf(-x)); }
__device__ __forceinline__ short f2b(float f){
    union { __hip_bfloat16 h; short s; } u; u.h = __float2bfloat16(f); return u.s;
}
__device__ __forceinline__ float b2f(short s){
    union { short s; __hip_bfloat16 h; } u; u.s = s; return __bfloat162float(u.h);
}
__device__ __forceinline__ void gload_lds16(const void* g, void* l){
    auto gp = reinterpret_cast<const __attribute__((address_space(1))) uint32_t*>(
        reinterpret_cast<uintptr_t>(g));
    auto lp = reinterpret_cast<__attribute__((address_space(3))) uint32_t*>(
        reinterpret_cast<uintptr_t>(l));
    __builtin_amdgcn_global_load_lds(gp, lp, 16, 0, 0);
}

// ---------------- prep: rmsnorm + transposes + dbc zero + residual copy -------
__device__ __forceinline__ void transp32(const float* in, short* outT,
                                         int R, int C, int Cout,
                                         int bx, int by, int t,
                                         float (*tile)[33]){
    int c0 = bx*32, r0 = by*32;
    int tx = t & 31, ty = t >> 5;
    #pragma unroll
    for (int p = 0; p < 4; p++){
        int r = r0 + ty + p*8, c = c0 + tx;
        tile[ty+p*8][tx] = (r < R && c < C) ? in[(size_t)r*C + c] : 0.f;
    }
    __syncthreads();
    #pragma unroll
    for (int p = 0; p < 4; p++){
        int c = c0 + ty + p*8;
        int r = r0 + tx;
        if (c < Cout && r < R)
            outT[(size_t)c*R + r] = f2b(tile[tx][ty+p*8]);
    }
}

// grid = 2048 rms + 2304 w1 + 1152 w3 + 192 wx + 160 dbc-zero + 384 out-copy = 6240
__global__ __launch_bounds__(256) void k_prep(const float* __restrict__ x,
                                              const float* __restrict__ nw,
                                              short* __restrict__ hb,
                                              const float* __restrict__ w1, short* __restrict__ Wb1,
                                              const float* __restrict__ w3, short* __restrict__ Wb3,
                                              const float* __restrict__ wx, short* __restrict__ Wbx,
                                              float* __restrict__ dbc,
                                              float* __restrict__ out){
    __shared__ float tile[32][33];
    int bid = blockIdx.x, t = threadIdx.x;
    if (bid < 2048){
        const float* xr = x + (size_t)bid * D_MODEL;
        float v[3]; float ss = 0.f;
        #pragma unroll
        for (int i = 0; i < 3; i++){ v[i] = xr[t + i*256]; ss += v[i]*v[i]; }
        #pragma unroll
        for (int o = 1; o < 64; o <<= 1) ss += __shfl_xor(ss, o, 64);
        int wave = t >> 6, lane = t & 63;
        if (lane == 0) tile[0][wave] = ss;
        __syncthreads();
        float tot = tile[0][0] + tile[0][1] + tile[0][2] + tile[0][3];
        float scale = rsqrtf(tot * (1.0f/768.0f) + 1e-6f);
        #pragma unroll
        for (int i = 0; i < 3; i++){
            int idx = t + i*256;
            hb[(size_t)bid*D_MODEL + idx] = f2b(v[i] * scale * nw[idx]);
        }
    } else if (bid < 4352){
        int id = bid - 2048;
        transp32(w1, Wb1, 768, 3072, 3072, id % 96, id / 96, t, tile);
    } else if (bid < 5504){
        int id = bid - 4352;
        transp32(w3, Wb3, 1536, 768, 768, id % 24, id / 24, t, tile);
    } else if (bid < 5696){
        int id = bid - 5504;
        transp32(wx, Wbx, 1536, DBC_N, DBC_NP, id % 4, id / 4, t, tile);
    } else if (bid < 5856){
        int id = bid - 5696;                      // zero 2048*80 floats
        size_t base = (size_t)id*1024 + t*4;
        *(float4*)&dbc[base] = make_float4(0.f,0.f,0.f,0.f);
    } else {
        int id = bid - 5856;                      // out = x (residual preload)
        #pragma unroll
        for (int p = 0; p < 4; p++){
            size_t off = (size_t)id*4096 + p*1024 + t*4;
            *(float4*)&out[off] = *(const float4*)&x[off];
        }
    }
}

// ---------------- MFMA bf16 GEMM, A[M][K] bf16, Bt[N][K] bf16 -----------------
// MODE 2: bf16 store. 3: fp32 atomicAdd (n<Nld).
// Wave microtile: (BM/2) x (BN/2). BM,BN multiples of 32; staging generalized.
template<int BM, int BN, int MODE, int KSPLIT>
__global__ __launch_bounds__(256) void k_mfma_bt(const short* __restrict__ A,
                                                 const short* __restrict__ Bt,
                                                 void* __restrict__ Cv,
                                                 int M, int N, int K, int Nld){
    constexpr int WM = BM/2, WN = BN/2;
    constexpr int FM = WM/16, FN = WN/16;
    constexpr int AU = BM*4;   // 16B staging units (4 per row of 32 bf16)
    constexpr int BU = BN*4;
    constexpr int AR = (AU + 255)/256;
    constexpr int BR = (BU + 255)/256;
    __shared__ short As[BM*32];
    __shared__ short Bs[BN*32];
    int t = threadIdx.x;
    int wave = t >> 6, lane = t & 63;
    int lm = lane & 15, lq = lane >> 4;
    int row0 = blockIdx.y * BM, col0 = blockIdx.x * BN;
    int wr = (wave >> 1) * WM, wc = (wave & 1) * WN;
    int kper = K / KSPLIT;
    int kbeg = blockIdx.z * kper;
    floatx4 acc[FM][FN];
    #pragma unroll
    for (int mi = 0; mi < FM; mi++)
        #pragma unroll
        for (int ni = 0; ni < FN; ni++)
            acc[mi][ni] = (floatx4){0.f,0.f,0.f,0.f};

    for (int k0 = kbeg; k0 < kbeg + kper; k0 += 32){
        #pragma unroll
        for (int r2 = 0; r2 < AR; r2++){
            int slot = r2*256 + t;
            if ((AU % 256 == 0) || slot < AU){
                int ar = slot >> 2, ak = (slot & 3)*8;
                gload_lds16(A + (size_t)(row0+ar)*K + k0 + ak, &As[slot*8]);
            }
        }
        #pragma unroll
        for (int r2 = 0; r2 < BR; r2++){
            int slot = r2*256 + t;
            if ((BU % 256 == 0) || slot < BU){
                int br = slot >> 2, bk = (slot & 3)*8;
                gload_lds16(Bt + (size_t)(col0+br)*K + k0 + bk, &Bs[slot*8]);
            }
        }
        __syncthreads();
        short8 af[FM], bfr[FN];
        #pragma unroll
        for (int mi = 0; mi < FM; mi++)
            af[mi] = *(const short8*)&As[(wr + mi*16 + lm)*32 + lq*8];
        #pragma unroll
        for (int ni = 0; ni < FN; ni++)
            bfr[ni] = *(const short8*)&Bs[(wc + ni*16 + lm)*32 + lq*8];
        #pragma unroll
        for (int mi = 0; mi < FM; mi++)
            #pragma unroll
            for (int ni = 0; ni < FN; ni++)
                acc[mi][ni] = __builtin_amdgcn_mfma_f32_16x16x32_bf16(
                                  af[mi], bfr[ni], acc[mi][ni], 0, 0, 0);
        __syncthreads();
    }
    float* Cf = (float*)Cv;
    short* Cs = (short*)Cv;
    #pragma unroll
    for (int mi = 0; mi < FM; mi++)
        #pragma unroll
        for (int ni = 0; ni < FN; ni++)
            #pragma unroll
            for (int r = 0; r < 4; r++){
                int m = row0 + wr + mi*16 + lq*4 + r;
                int n = col0 + wc + ni*16 + lm;
                float v = acc[mi][ni][r];
                if constexpr (MODE == 2){
                    Cs[(size_t)m*Nld + n] = f2b(v);
                } else {
                    if (n < Nld) atomicAdd(&Cf[(size_t)m*Nld + n], v);
                }
            }
}

// ---------------- causal depthwise conv + bias + SiLU -> bf16 (8-wide) --------
// thread handles 8 consecutive channels: 4x short8 tap loads + 1 short8 store.
__global__ __launch_bounds__(256) void k_conv(const short* __restrict__ xzb,
                                              const float* __restrict__ cw,
                                              const float* __restrict__ cb,
                                              short* __restrict__ xcb){
    int t = blockIdx.x * 256 + threadIdx.x;     // over NROWS * (D_INNER/8)
    int d8 = t % (D_INNER/8);
    int r  = t / (D_INNER/8);
    int d0 = d8 * 8;
    int l = r % SEQ;
    short8 tap[4];
    #pragma unroll
    for (int k = 0; k < 4; k++){
        if (l - 3 + k >= 0)
            tap[k] = *(const short8*)&xzb[(size_t)(r - 3 + k)*3072 + d0];
        else
            tap[k] = (short8){0,0,0,0,0,0,0,0};
    }
    short8 outv;
    #pragma unroll
    for (int j = 0; j < 8; j++){
        int d = d0 + j;
        const float4 w4 = *(const float4*)&cw[d*4];
        float acc = cb[d];
        acc += b2f(tap[0][j]) * w4.x;
        acc += b2f(tap[1][j]) * w4.y;
        acc += b2f(tap[2][j]) * w4.z;
        acc += b2f(tap[3][j]) * w4.w;
        outv[j] = f2b(siluf(acc));
    }
    *(short8*)&xcb[(size_t)r*D_INNER + d0] = outv;
}

// ================= chunked selective scan (dtproj fused into phase A) =========
// thread t = (b*NCHUNK + chunk)*D_INNER + d; Ap/Hl/carry bf16, layout [t][n].

__global__ __launch_bounds__(256) void k_scanA(const short* __restrict__ xcb,
                                               const float* __restrict__ dbc,
                                               const float* __restrict__ wdt,
                                               const float* __restrict__ bdt,
                                               const float* __restrict__ A_log,
                                               short* __restrict__ Apb,
                                               short* __restrict__ Hlb,
                                               short* __restrict__ dtb){
    int t = blockIdx.x * 256 + threadIdx.x;
    int d = t % D_INNER;
    int bc = t / D_INNER;
    int chunk = bc % NCHUNK, b = bc / NCHUNK;
    int r0 = b*SEQ + chunk*CHUNK;

    float dt16[CHUNK];
    {
        float wr[DT_RANK];
        #pragma unroll
        for (int k = 0; k < DT_RANK; k++) wr[k] = wdt[k*D_INNER + d];
        float bj = bdt[d];
        for (int l = 0; l < CHUNK; l++){
            const float* dl = &dbc[(size_t)(r0+l)*DBC_N];   // wave-uniform bcast
            float acc = bj;
            #pragma unroll
            for (int k = 0; k < DT_RANK; k++) acc += dl[k] * wr[k];
            float sp = (acc > 20.f) ? acc : __logf(1.f + __expf(acc));
            dt16[l] = sp;
            dtb[(size_t)(r0+l)*D_INNER + d] = f2b(sp);
        }
    }

    float A[16], h[16], aP[16];
    const float4* al = (const float4*)&A_log[d*D_STATE];
    #pragma unroll
    for (int i = 0; i < 4; i++){
        float4 v = al[i];
        A[4*i+0] = -__expf(v.x); A[4*i+1] = -__expf(v.y);
        A[4*i+2] = -__expf(v.z); A[4*i+3] = -__expf(v.w);
    }
    #pragma unroll
    for (int n = 0; n < 16; n++){ h[n] = 0.f; aP[n] = 1.f; }
    for (int l = 0; l < CHUNK; l++){
        int r = r0 + l;
        float dtv = dt16[l];
        float xcv = b2f(xcb[(size_t)r*D_INNER + d]);
        const float4* bp = (const float4*)&dbc[(size_t)r*DBC_N + DT_RANK];
        float Bm[16];
        #pragma unroll
        for (int i = 0; i < 4; i++){
            float4 v = bp[i];
            Bm[4*i+0]=v.x; Bm[4*i+1]=v.y; Bm[4*i+2]=v.z; Bm[4*i+3]=v.w;
        }
        float comm = dtv * xcv;
        #pragma unroll
        for (int n = 0; n < 16; n++){
            float a = __expf(dtv * A[n]);
            h[n] = a*h[n] + comm*Bm[n];
            aP[n] *= a;
        }
    }
    short8 s0, s1;
    #pragma unroll
    for (int i = 0; i < 8; i++){ s0[i] = f2b(aP[i]);  s1[i] = f2b(aP[8+i]); }
    *(short8*)&Apb[(size_t)t*16]     = s0;
    *(short8*)&Apb[(size_t)t*16 + 8] = s1;
    #pragma unroll
    for (int i = 0; i < 8; i++){ s0[i] = f2b(h[i]);   s1[i] = f2b(h[8+i]); }
    *(short8*)&Hlb[(size_t)t*16]     = s0;
    *(short8*)&Hlb[(size_t)t*16 + 8] = s1;
}

// carry aliases Apb: each idx read before written.
__global__ __launch_bounds__(256) void k_scanB(const short* Apb,
                                               const short* Hlb,
                                               short* carry){
    int t = blockIdx.x * 256 + threadIdx.x;    // over [b][d][n] = 49152
    int dn = t % (D_INNER*16);
    int b  = t / (D_INNER*16);
    float c = 0.f;
    #pragma unroll 4
    for (int ch = 0; ch < NCHUNK; ch++){
        size_t idx = ((size_t)((b*NCHUNK + ch)*D_INNER))*16 + dn;
        float a  = b2f(Apb[idx]);
        float hl = b2f(Hlb[idx]);
        carry[idx] = f2b(c);
        c = a*c + hl;
    }
}

__global__ __launch_bounds__(256) void k_scanC(const short* __restrict__ dtb,
                                               const short* __restrict__ xcb,
                                               const float* __restrict__ dbc,
                                               const short* __restrict__ xzb,
                                               const float* __restrict__ A_log,
                                               const float* __restrict__ Dp,
                                               const short* __restrict__ carry,
                                               short* __restrict__ yb){
    int t = blockIdx.x * 256 + threadIdx.x;
    int d = t % D_INNER;
    int bc = t / D_INNER;
    int chunk = bc % NCHUNK, b = bc / NCHUNK;
    float A[16], h[16];
    const float4* al = (const float4*)&A_log[d*D_STATE];
    #pragma unroll
    for (int i = 0; i < 4; i++){
        float4 v = al[i];
        A[4*i+0] = -__expf(v.x); A[4*i+1] = -__expf(v.y);
        A[4*i+2] = -__expf(v.z); A[4*i+3] = -__expf(v.w);
    }
    {
        short8 c0 = *(const short8*)&carry[(size_t)t*16];
        short8 c1 = *(const short8*)&carry[(size_t)t*16 + 8];
        #pragma unroll
        for (int i = 0; i < 8; i++){ h[i] = b2f(c0[i]); h[8+i] = b2f(c1[i]); }
    }
    float Dv = Dp[d];
    int r0 = b*SEQ + chunk*CHUNK;
    for (int l = 0; l < CHUNK; l++){
        int r = r0 + l;
        float dtv = b2f(dtb[(size_t)r*D_INNER + d]);
        float xcv = b2f(xcb[(size_t)r*D_INNER + d]);
        const float4* bp = (const float4*)&dbc[(size_t)r*DBC_N + DT_RANK];
        float Bm[16], Cm[16];
        #pragma unroll
        for (int i = 0; i < 4; i++){
            float4 v = bp[i];
            Bm[4*i+0]=v.x; Bm[4*i+1]=v.y; Bm[4*i+2]=v.z; Bm[4*i+3]=v.w;
            float4 w = bp[4+i];
            Cm[4*i+0]=w.x; Cm[4*i+1]=w.y; Cm[4*i+2]=w.z; Cm[4*i+3]=w.w;
        }
        float comm = dtv * xcv;
        float yv = 0.f;
        #pragma unroll
        for (int n = 0; n < 16; n++){
            float a = __expf(dtv * A[n]);
            h[n] = a*h[n] + comm*Bm[n];
            yv += h[n]*Cm[n];
        }
        float z = b2f(xzb[(size_t)r*(2*D_INNER) + D_INNER + d]);
        yb[(size_t)r*D_INNER + d] = f2b((yv + Dv*xcv) * siluf(z));
    }
}

extern "C" void kernel_launch(void* const* d_in, const int* in_sizes, int n_in,
                              void* d_out, int out_size, void* d_ws, size_t ws_size,
                              hipStream_t stream) {
    const float* x         = (const float*)d_in[0];
    const float* norm_w    = (const float*)d_in[1];
    const float* in_proj_w = (const float*)d_in[2];
    const float* conv_w    = (const float*)d_in[3];
    const float* conv_b    = (const float*)d_in[4];
    const float* x_proj_w  = (const float*)d_in[5];
    const float* dt_proj_w = (const float*)d_in[6];
    const float* dt_proj_b = (const float*)d_in[7];
    const float* A_log     = (const float*)d_in[8];
    const float* Dp        = (const float*)d_in[9];
    const float* out_proj_w= (const float*)d_in[10];
    float* out = (float*)d_out;

    char* p = (char*)d_ws;
    short* hb  = (short*)p; p += (size_t)NROWS*D_MODEL*2;
    short* xzb = (short*)p; p += (size_t)NROWS*3072*2;
    short* xcb = (short*)p; p += (size_t)NROWS*D_INNER*2;
    float* dbc = (float*)p; p += (size_t)NROWS*DBC_N*4;
    short* dtb = (short*)p; p += (size_t)NROWS*D_INNER*2;
    short* yb  = (short*)p; p += (size_t)NROWS*D_INNER*2;
    short* Apb = (short*)p; p += SCAN_T*2;                     // aliased as carry
    short* Hlb = (short*)p; p += SCAN_T*2;
    short* Wb1 = (short*)p; p += (size_t)3072*768*2;
    short* Wb3 = (short*)p; p += (size_t)768*1536*2;
    short* Wbx = (short*)p; p += (size_t)DBC_NP*1536*2;
    short* cr  = Apb;  // alias: k_scanB reads before writing at each idx

    // rmsnorm + transposes + dbc zero + residual preload into out
    k_prep<<<6240, 256, 0, stream>>>(x, norm_w, hb, in_proj_w, Wb1,
                                     out_proj_w, Wb3, x_proj_w, Wbx, dbc, out);

    // in-proj: M=2048, N=3072, K=768, 128x96 tiles -> 512 blocks (2/CU), bf16
    k_mfma_bt<128,96,2,1><<<dim3(3072/96, NROWS/128), 256, 0, stream>>>(
        hb, Wb1, xzb, NROWS, 3072, D_MODEL, 3072);

    // conv (8-wide vectorized, coalesced)
    k_conv<<<(NROWS*(D_INNER/8))/256, 256, 0, stream>>>(xzb, conv_w, conv_b, xcb);

    // x-proj: M=2048, N=128(pad of 80), K=1536, split-K=8 -> 512 blocks
    k_mfma_bt<64,64,3,8><<<dim3(DBC_NP/64, NROWS/64, 8), 256, 0, stream>>>(
        xcb, Wbx, dbc, NROWS, DBC_NP, D_INNER, DBC_N);

    // scan: A (dtproj fused) -> B -> C   (bf16 intermediates)
    k_scanA<<<SCAN_G/256, 256, 0, stream>>>(xcb, dbc, dt_proj_w, dt_proj_b,
                                            A_log, Apb, Hlb, dtb);
    k_scanB<<<(BATCH*D_INNER*D_STATE)/256, 256, 0, stream>>>(Apb, Hlb, cr);
    k_scanC<<<SCAN_G/256, 256, 0, stream>>>(dtb, xcb, dbc, xzb, A_log, Dp,
                                            cr, yb);

    // out-proj: M=2048, N=768, K=1536, split-K=2 -> 768 blocks, atomicAdd
    // (residual preloaded into out by k_prep)
    k_mfma_bt<64,64,3,2><<<dim3(768/64, NROWS/64, 2), 256, 0, stream>>>(
        yb, Wb3, out, NROWS, 768, D_INNER, 768);
}

// Round 12
// 225.289 us; speedup vs baseline: 1.1139x; 1.0039x over previous
//
#include <hip/hip_runtime.h>
#include <hip/hip_bf16.h>
#include <math.h>
#include <stdint.h>

#define D_MODEL 768
#define D_STATE 16
#define D_INNER 1536
#define DT_RANK 48
#define BATCH   2
#define SEQ     1024
#define NROWS   (BATCH*SEQ)      // 2048
#define DBC_N   80
#define DBC_NP  96               // padded N for xproj MFMA (was 128)
#define NCHUNK  64
#define CHUNK   16               // SEQ/NCHUNK
#define SCAN_G  (BATCH*NCHUNK*D_INNER)           // 196608 threads
#define SCAN_T  ((size_t)SCAN_G*D_STATE)         // 3145728 elems

typedef short short8 __attribute__((ext_vector_type(8)));
typedef float floatx4 __attribute__((ext_vector_type(4)));

__device__ __forceinline__ float siluf(float x){ return x / (1.0f + __expf(-x)); }
__device__ __forceinline__ short f2b(float f){
    union { __hip_bfloat16 h; short s; } u; u.h = __float2bfloat16(f); return u.s;
}
__device__ __forceinline__ float b2f(short s){
    union { short s; __hip_bfloat16 h; } u; u.s = s; return __bfloat162float(u.h);
}
__device__ __forceinline__ void gload_lds16(const void* g, void* l){
    auto gp = reinterpret_cast<const __attribute__((address_space(1))) uint32_t*>(
        reinterpret_cast<uintptr_t>(g));
    auto lp = reinterpret_cast<__attribute__((address_space(3))) uint32_t*>(
        reinterpret_cast<uintptr_t>(l));
    __builtin_amdgcn_global_load_lds(gp, lp, 16, 0, 0);
}

// ---------------- prep: rmsnorm + transposes + dbc zero + residual copy -------
__device__ __forceinline__ void transp32(const float* in, short* outT,
                                         int R, int C, int Cout,
                                         int bx, int by, int t,
                                         float (*tile)[33]){
    int c0 = bx*32, r0 = by*32;
    int tx = t & 31, ty = t >> 5;
    #pragma unroll
    for (int p = 0; p < 4; p++){
        int r = r0 + ty + p*8, c = c0 + tx;
        tile[ty+p*8][tx] = (r < R && c < C) ? in[(size_t)r*C + c] : 0.f;
    }
    __syncthreads();
    #pragma unroll
    for (int p = 0; p < 4; p++){
        int c = c0 + ty + p*8;
        int r = r0 + tx;
        if (c < Cout && r < R)
            outT[(size_t)c*R + r] = f2b(tile[tx][ty+p*8]);
    }
}

// grid = 2048 rms + 2304 w1 + 1152 w3 + 144 wx + 160 dbc-zero + 384 out-copy = 6192
__global__ __launch_bounds__(256) void k_prep(const float* __restrict__ x,
                                              const float* __restrict__ nw,
                                              short* __restrict__ hb,
                                              const float* __restrict__ w1, short* __restrict__ Wb1,
                                              const float* __restrict__ w3, short* __restrict__ Wb3,
                                              const float* __restrict__ wx, short* __restrict__ Wbx,
                                              float* __restrict__ dbc,
                                              float* __restrict__ out){
    __shared__ float tile[32][33];
    int bid = blockIdx.x, t = threadIdx.x;
    if (bid < 2048){
        const float* xr = x + (size_t)bid * D_MODEL;
        float v[3]; float ss = 0.f;
        #pragma unroll
        for (int i = 0; i < 3; i++){ v[i] = xr[t + i*256]; ss += v[i]*v[i]; }
        #pragma unroll
        for (int o = 1; o < 64; o <<= 1) ss += __shfl_xor(ss, o, 64);
        int wave = t >> 6, lane = t & 63;
        if (lane == 0) tile[0][wave] = ss;
        __syncthreads();
        float tot = tile[0][0] + tile[0][1] + tile[0][2] + tile[0][3];
        float scale = rsqrtf(tot * (1.0f/768.0f) + 1e-6f);
        #pragma unroll
        for (int i = 0; i < 3; i++){
            int idx = t + i*256;
            hb[(size_t)bid*D_MODEL + idx] = f2b(v[i] * scale * nw[idx]);
        }
    } else if (bid < 4352){
        int id = bid - 2048;
        transp32(w1, Wb1, 768, 3072, 3072, id % 96, id / 96, t, tile);
    } else if (bid < 5504){
        int id = bid - 4352;
        transp32(w3, Wb3, 1536, 768, 768, id % 24, id / 24, t, tile);
    } else if (bid < 5648){
        int id = bid - 5504;
        transp32(wx, Wbx, 1536, DBC_N, DBC_NP, id % 3, id / 3, t, tile);
    } else if (bid < 5808){
        int id = bid - 5648;                      // zero 2048*80 floats
        size_t base = (size_t)id*1024 + t*4;
        *(float4*)&dbc[base] = make_float4(0.f,0.f,0.f,0.f);
    } else {
        int id = bid - 5808;                      // out = x (residual preload)
        #pragma unroll
        for (int p = 0; p < 4; p++){
            size_t off = (size_t)id*4096 + p*1024 + t*4;
            *(float4*)&out[off] = *(const float4*)&x[off];
        }
    }
}

// ---------------- MFMA bf16 GEMM, A[M][K] bf16, Bt[N][K] bf16 -----------------
// MODE 2: bf16 store. 3: fp32 atomicAdd (n<Nld).
template<int BM, int BN, int MODE, int KSPLIT>
__global__ __launch_bounds__(256) void k_mfma_bt(const short* __restrict__ A,
                                                 const short* __restrict__ Bt,
                                                 void* __restrict__ Cv,
                                                 int M, int N, int K, int Nld){
    constexpr int WM = BM/2, WN = BN/2;
    constexpr int FM = WM/16, FN = WN/16;
    constexpr int AU = BM*4;   // 16B staging units (4 per row of 32 bf16)
    constexpr int BU = BN*4;
    constexpr int AR = (AU + 255)/256;
    constexpr int BR = (BU + 255)/256;
    __shared__ short As[BM*32];
    __shared__ short Bs[BN*32];
    int t = threadIdx.x;
    int wave = t >> 6, lane = t & 63;
    int lm = lane & 15, lq = lane >> 4;
    int row0 = blockIdx.y * BM, col0 = blockIdx.x * BN;
    int wr = (wave >> 1) * WM, wc = (wave & 1) * WN;
    int kper = K / KSPLIT;
    int kbeg = blockIdx.z * kper;
    floatx4 acc[FM][FN];
    #pragma unroll
    for (int mi = 0; mi < FM; mi++)
        #pragma unroll
        for (int ni = 0; ni < FN; ni++)
            acc[mi][ni] = (floatx4){0.f,0.f,0.f,0.f};

    for (int k0 = kbeg; k0 < kbeg + kper; k0 += 32){
        #pragma unroll
        for (int r2 = 0; r2 < AR; r2++){
            int slot = r2*256 + t;
            if ((AU % 256 == 0) || slot < AU){
                int ar = slot >> 2, ak = (slot & 3)*8;
                gload_lds16(A + (size_t)(row0+ar)*K + k0 + ak, &As[slot*8]);
            }
        }
        #pragma unroll
        for (int r2 = 0; r2 < BR; r2++){
            int slot = r2*256 + t;
            if ((BU % 256 == 0) || slot < BU){
                int br = slot >> 2, bk = (slot & 3)*8;
                gload_lds16(Bt + (size_t)(col0+br)*K + k0 + bk, &Bs[slot*8]);
            }
        }
        __syncthreads();
        short8 af[FM], bfr[FN];
        #pragma unroll
        for (int mi = 0; mi < FM; mi++)
            af[mi] = *(const short8*)&As[(wr + mi*16 + lm)*32 + lq*8];
        #pragma unroll
        for (int ni = 0; ni < FN; ni++)
            bfr[ni] = *(const short8*)&Bs[(wc + ni*16 + lm)*32 + lq*8];
        #pragma unroll
        for (int mi = 0; mi < FM; mi++)
            #pragma unroll
            for (int ni = 0; ni < FN; ni++)
                acc[mi][ni] = __builtin_amdgcn_mfma_f32_16x16x32_bf16(
                                  af[mi], bfr[ni], acc[mi][ni], 0, 0, 0);
        __syncthreads();
    }
    float* Cf = (float*)Cv;
    short* Cs = (short*)Cv;
    #pragma unroll
    for (int mi = 0; mi < FM; mi++)
        #pragma unroll
        for (int ni = 0; ni < FN; ni++)
            #pragma unroll
            for (int r = 0; r < 4; r++){
                int m = row0 + wr + mi*16 + lq*4 + r;
                int n = col0 + wc + ni*16 + lm;
                float v = acc[mi][ni][r];
                if constexpr (MODE == 2){
                    Cs[(size_t)m*Nld + n] = f2b(v);
                } else {
                    if (n < Nld) atomicAdd(&Cf[(size_t)m*Nld + n], v);
                }
            }
}

// ---------------- causal depthwise conv + bias + SiLU -> bf16 (8-wide) --------
__global__ __launch_bounds__(256) void k_conv(const short* __restrict__ xzb,
                                              const float* __restrict__ cw,
                                              const float* __restrict__ cb,
                                              short* __restrict__ xcb){
    int t = blockIdx.x * 256 + threadIdx.x;     // over NROWS * (D_INNER/8)
    int d8 = t % (D_INNER/8);
    int r  = t / (D_INNER/8);
    int d0 = d8 * 8;
    int l = r % SEQ;
    short8 tap[4];
    #pragma unroll
    for (int k = 0; k < 4; k++){
        if (l - 3 + k >= 0)
            tap[k] = *(const short8*)&xzb[(size_t)(r - 3 + k)*3072 + d0];
        else
            tap[k] = (short8){0,0,0,0,0,0,0,0};
    }
    short8 outv;
    #pragma unroll
    for (int j = 0; j < 8; j++){
        int d = d0 + j;
        const float4 w4 = *(const float4*)&cw[d*4];
        float acc = cb[d];
        acc += b2f(tap[0][j]) * w4.x;
        acc += b2f(tap[1][j]) * w4.y;
        acc += b2f(tap[2][j]) * w4.z;
        acc += b2f(tap[3][j]) * w4.w;
        outv[j] = f2b(siluf(acc));
    }
    *(short8*)&xcb[(size_t)r*D_INNER + d0] = outv;
}

// ================= chunked selective scan (dtproj fused into phase A) =========
// thread t = (b*NCHUNK + chunk)*D_INNER + d; Ap/Hl/carry bf16, layout [t][n].

__global__ __launch_bounds__(256) void k_scanA(const short* __restrict__ xcb,
                                               const float* __restrict__ dbc,
                                               const float* __restrict__ wdt,
                                               const float* __restrict__ bdt,
                                               const float* __restrict__ A_log,
                                               short* __restrict__ Apb,
                                               short* __restrict__ Hlb,
                                               short* __restrict__ dtb){
    int t = blockIdx.x * 256 + threadIdx.x;
    int d = t % D_INNER;
    int bc = t / D_INNER;
    int chunk = bc % NCHUNK, b = bc / NCHUNK;
    int r0 = b*SEQ + chunk*CHUNK;

    float dt16[CHUNK];
    {
        float wr[DT_RANK];
        #pragma unroll
        for (int k = 0; k < DT_RANK; k++) wr[k] = wdt[k*D_INNER + d];
        float bj = bdt[d];
        for (int l = 0; l < CHUNK; l++){
            const float* dl = &dbc[(size_t)(r0+l)*DBC_N];   // wave-uniform bcast
            float acc = bj;
            #pragma unroll
            for (int k = 0; k < DT_RANK; k++) acc += dl[k] * wr[k];
            float sp = (acc > 20.f) ? acc : __logf(1.f + __expf(acc));
            dt16[l] = sp;
            dtb[(size_t)(r0+l)*D_INNER + d] = f2b(sp);
        }
    }

    float A[16], h[16], aP[16];
    const float4* al = (const float4*)&A_log[d*D_STATE];
    #pragma unroll
    for (int i = 0; i < 4; i++){
        float4 v = al[i];
        A[4*i+0] = -__expf(v.x); A[4*i+1] = -__expf(v.y);
        A[4*i+2] = -__expf(v.z); A[4*i+3] = -__expf(v.w);
    }
    #pragma unroll
    for (int n = 0; n < 16; n++){ h[n] = 0.f; aP[n] = 1.f; }
    for (int l = 0; l < CHUNK; l++){
        int r = r0 + l;
        float dtv = dt16[l];
        float xcv = b2f(xcb[(size_t)r*D_INNER + d]);
        const float4* bp = (const float4*)&dbc[(size_t)r*DBC_N + DT_RANK];
        float Bm[16];
        #pragma unroll
        for (int i = 0; i < 4; i++){
            float4 v = bp[i];
            Bm[4*i+0]=v.x; Bm[4*i+1]=v.y; Bm[4*i+2]=v.z; Bm[4*i+3]=v.w;
        }
        float comm = dtv * xcv;
        #pragma unroll
        for (int n = 0; n < 16; n++){
            float a = __expf(dtv * A[n]);
            h[n] = a*h[n] + comm*Bm[n];
            aP[n] *= a;
        }
    }
    short8 s0, s1;
    #pragma unroll
    for (int i = 0; i < 8; i++){ s0[i] = f2b(aP[i]);  s1[i] = f2b(aP[8+i]); }
    *(short8*)&Apb[(size_t)t*16]     = s0;
    *(short8*)&Apb[(size_t)t*16 + 8] = s1;
    #pragma unroll
    for (int i = 0; i < 8; i++){ s0[i] = f2b(h[i]);   s1[i] = f2b(h[8+i]); }
    *(short8*)&Hlb[(size_t)t*16]     = s0;
    *(short8*)&Hlb[(size_t)t*16 + 8] = s1;
}

// carry aliases Apb: each idx read before written. 2 states per thread (dword).
__global__ __launch_bounds__(256) void k_scanB(const short* Apb,
                                               const short* Hlb,
                                               short* carry){
    int t = blockIdx.x * 256 + threadIdx.x;    // over [b][d][n/2] = 24576
    int dn2 = t % (D_INNER*8);
    int b   = t / (D_INNER*8);
    float c0 = 0.f, c1 = 0.f;
    #pragma unroll 4
    for (int ch = 0; ch < NCHUNK; ch++){
        size_t idx = ((size_t)((b*NCHUNK + ch)*D_INNER))*16 + (size_t)dn2*2;
        union { int i; short s[2]; } ua, uh, uc;
        ua.i = *(const int*)&Apb[idx];
        uh.i = *(const int*)&Hlb[idx];
        uc.s[0] = f2b(c0); uc.s[1] = f2b(c1);
        *(int*)&carry[idx] = uc.i;
        c0 = b2f(ua.s[0])*c0 + b2f(uh.s[0]);
        c1 = b2f(ua.s[1])*c1 + b2f(uh.s[1]);
    }
}

__global__ __launch_bounds__(256) void k_scanC(const short* __restrict__ dtb,
                                               const short* __restrict__ xcb,
                                               const float* __restrict__ dbc,
                                               const short* __restrict__ xzb,
                                               const float* __restrict__ A_log,
                                               const float* __restrict__ Dp,
                                               const short* __restrict__ carry,
                                               short* __restrict__ yb){
    int t = blockIdx.x * 256 + threadIdx.x;
    int d = t % D_INNER;
    int bc = t / D_INNER;
    int chunk = bc % NCHUNK, b = bc / NCHUNK;
    float A[16], h[16];
    const float4* al = (const float4*)&A_log[d*D_STATE];
    #pragma unroll
    for (int i = 0; i < 4; i++){
        float4 v = al[i];
        A[4*i+0] = -__expf(v.x); A[4*i+1] = -__expf(v.y);
        A[4*i+2] = -__expf(v.z); A[4*i+3] = -__expf(v.w);
    }
    {
        short8 c0 = *(const short8*)&carry[(size_t)t*16];
        short8 c1 = *(const short8*)&carry[(size_t)t*16 + 8];
        #pragma unroll
        for (int i = 0; i < 8; i++){ h[i] = b2f(c0[i]); h[8+i] = b2f(c1[i]); }
    }
    float Dv = Dp[d];
    int r0 = b*SEQ + chunk*CHUNK;
    for (int l = 0; l < CHUNK; l++){
        int r = r0 + l;
        float dtv = b2f(dtb[(size_t)r*D_INNER + d]);
        float xcv = b2f(xcb[(size_t)r*D_INNER + d]);
        const float4* bp = (const float4*)&dbc[(size_t)r*DBC_N + DT_RANK];
        float Bm[16], Cm[16];
        #pragma unroll
        for (int i = 0; i < 4; i++){
            float4 v = bp[i];
            Bm[4*i+0]=v.x; Bm[4*i+1]=v.y; Bm[4*i+2]=v.z; Bm[4*i+3]=v.w;
            float4 w = bp[4+i];
            Cm[4*i+0]=w.x; Cm[4*i+1]=w.y; Cm[4*i+2]=w.z; Cm[4*i+3]=w.w;
        }
        float comm = dtv * xcv;
        float yv = 0.f;
        #pragma unroll
        for (int n = 0; n < 16; n++){
            float a = __expf(dtv * A[n]);
            h[n] = a*h[n] + comm*Bm[n];
            yv += h[n]*Cm[n];
        }
        float z = b2f(xzb[(size_t)r*(2*D_INNER) + D_INNER + d]);
        yb[(size_t)r*D_INNER + d] = f2b((yv + Dv*xcv) * siluf(z));
    }
}

extern "C" void kernel_launch(void* const* d_in, const int* in_sizes, int n_in,
                              void* d_out, int out_size, void* d_ws, size_t ws_size,
                              hipStream_t stream) {
    const float* x         = (const float*)d_in[0];
    const float* norm_w    = (const float*)d_in[1];
    const float* in_proj_w = (const float*)d_in[2];
    const float* conv_w    = (const float*)d_in[3];
    const float* conv_b    = (const float*)d_in[4];
    const float* x_proj_w  = (const float*)d_in[5];
    const float* dt_proj_w = (const float*)d_in[6];
    const float* dt_proj_b = (const float*)d_in[7];
    const float* A_log     = (const float*)d_in[8];
    const float* Dp        = (const float*)d_in[9];
    const float* out_proj_w= (const float*)d_in[10];
    float* out = (float*)d_out;

    char* p = (char*)d_ws;
    short* hb  = (short*)p; p += (size_t)NROWS*D_MODEL*2;
    short* xzb = (short*)p; p += (size_t)NROWS*3072*2;
    short* xcb = (short*)p; p += (size_t)NROWS*D_INNER*2;
    float* dbc = (float*)p; p += (size_t)NROWS*DBC_N*4;
    short* dtb = (short*)p; p += (size_t)NROWS*D_INNER*2;
    short* yb  = (short*)p; p += (size_t)NROWS*D_INNER*2;
    short* Apb = (short*)p; p += SCAN_T*2;                     // aliased as carry
    short* Hlb = (short*)p; p += SCAN_T*2;
    short* Wb1 = (short*)p; p += (size_t)3072*768*2;
    short* Wb3 = (short*)p; p += (size_t)768*1536*2;
    short* Wbx = (short*)p; p += (size_t)DBC_NP*1536*2;
    short* cr  = Apb;  // alias: k_scanB reads before writing at each idx

    // rmsnorm + transposes + dbc zero + residual preload into out
    k_prep<<<6192, 256, 0, stream>>>(x, norm_w, hb, in_proj_w, Wb1,
                                     out_proj_w, Wb3, x_proj_w, Wbx, dbc, out);

    // in-proj: M=2048, N=3072, K=768, 128x96 tiles -> 512 blocks (2/CU), bf16
    k_mfma_bt<128,96,2,1><<<dim3(3072/96, NROWS/128), 256, 0, stream>>>(
        hb, Wb1, xzb, NROWS, 3072, D_MODEL, 3072);

    // conv (8-wide vectorized, coalesced)
    k_conv<<<(NROWS*(D_INNER/8))/256, 256, 0, stream>>>(xzb, conv_w, conv_b, xcb);

    // x-proj: M=2048, N=96(pad of 80), K=1536, split-K=8 -> 256 blocks
    k_mfma_bt<64,96,3,8><<<dim3(DBC_NP/96, NROWS/64, 8), 256, 0, stream>>>(
        xcb, Wbx, dbc, NROWS, DBC_NP, D_INNER, DBC_N);

    // scan: A (dtproj fused) -> B (2-wide) -> C   (bf16 intermediates)
    k_scanA<<<SCAN_G/256, 256, 0, stream>>>(xcb, dbc, dt_proj_w, dt_proj_b,
                                            A_log, Apb, Hlb, dtb);
    k_scanB<<<(BATCH*D_INNER*D_STATE/2)/256, 256, 0, stream>>>(Apb, Hlb, cr);
    k_scanC<<<SCAN_G/256, 256, 0, stream>>>(dtb, xcb, dbc, xzb, A_log, Dp,
                                            cr, yb);

    // out-proj: M=2048, N=768, K=1536, split-K=2 -> 768 blocks, atomicAdd
    // (residual preloaded into out by k_prep)
    k_mfma_bt<64,64,3,2><<<dim3(768/64, NROWS/64, 2), 256, 0, stream>>>(
        yb, Wb3, out, NROWS, 768, D_INNER, 768);
}